// Round 20
// baseline (723.560 us; speedup 1.0000x reference)
//
#include <hip/hip_runtime.h>

#define T_TOK 4096
#define DM 1024
#define DF 4096
#define NE 8
#define BM 256
#define RCAP 10240      // 8192 + 8*256 worst-case padding
#define MAXT 40         // RCAP / BM (256-row tiles)
#define MAXT2 80        // RCAP / 128 (128-row tiles, gemm2)
#define ACH_B 32768     // [256][64] fp16 swizzled A-chunk
#define CHUNK_B 8192    // [64][64] fp16 swizzled weight chunk

typedef _Float16 f16x8 __attribute__((ext_vector_type(8)));
typedef float f32x4 __attribute__((ext_vector_type(4)));

#define MFMA16(a, b, c) __builtin_amdgcn_mfma_f32_16x16x32_f16(a, b, c, 0, 0, 0)
#define RAW_BAR() __builtin_amdgcn_s_barrier()
#define VMCNT(n) asm volatile("s_waitcnt vmcnt(" #n ")" ::: "memory")
#define LGKMCNT0() asm volatile("s_waitcnt lgkmcnt(0)" ::: "memory")

__device__ __forceinline__ ushort f2h_bits(float f) {
    _Float16 h = (_Float16)f;
    return __builtin_bit_cast(unsigned short, h);
}

__device__ __forceinline__ unsigned int pk2(float a, float b) {
    return __builtin_bit_cast(unsigned int, __builtin_amdgcn_cvt_pkrtz(a, b));
}

__device__ __forceinline__ uint4 pack8f(float4 a, float4 b) {
    uint4 r;
    r.x = pk2(a.x, a.y); r.y = pk2(a.z, a.w);
    r.z = pk2(b.x, b.y); r.w = pk2(b.z, b.w);
    return r;
}

// async global->LDS, 16B per lane; lds ptr wave-uniform
__device__ __forceinline__ void gll16(const void* g, void* l) {
    __builtin_amdgcn_global_load_lds(
        (const __attribute__((address_space(1))) unsigned int*)g,
        (__attribute__((address_space(3))) unsigned int*)l, 16, 0, 0);
}

// ---------------- init ----------------
__global__ __launch_bounds__(256) void k_init(int* __restrict__ misc,
                                              int* __restrict__ row_tok) {
    int i = blockIdx.x * 256 + threadIdx.x;
    if (i < RCAP) row_tok[i] = -1;
    if (i < 256) misc[i] = 0;   // cnt8 fill8 poff8 texp40 texp2_80 ntp2
}

// ---------------- router ----------------
__global__ __launch_bounds__(64) void k_router(const float* __restrict__ x,
                                               const float* __restrict__ Wr,
                                               float* __restrict__ probs,
                                               int* __restrict__ topi,
                                               float* __restrict__ topw,
                                               int* __restrict__ cnt) {
    int t = blockIdx.x;
    int lane = threadIdx.x;
    const float* xr = x + (size_t)t * DM;
    float s[NE];
#pragma unroll
    for (int e = 0; e < NE; e++) s[e] = 0.f;
    for (int j = lane; j < DM; j += 64) {
        float xv = xr[j];
#pragma unroll
        for (int e = 0; e < NE; e++) s[e] += xv * Wr[e * DM + j];
    }
#pragma unroll
    for (int off = 32; off > 0; off >>= 1) {
#pragma unroll
        for (int e = 0; e < NE; e++) s[e] += __shfl_xor(s[e], off, 64);
    }
    if (lane == 0) {
        float mx = s[0];
#pragma unroll
        for (int e = 1; e < NE; e++) mx = fmaxf(mx, s[e]);
        float ex[NE], sum = 0.f;
#pragma unroll
        for (int e = 0; e < NE; e++) { ex[e] = expf(s[e] - mx); sum += ex[e]; }
        float inv = 1.f / sum;
        float p[NE];
#pragma unroll
        for (int e = 0; e < NE; e++) { p[e] = ex[e] * inv; probs[t * NE + e] = p[e]; }
        int i0 = 0;
#pragma unroll
        for (int e = 1; e < NE; e++) if (p[e] > p[i0]) i0 = e;
        int i1 = (i0 == 0) ? 1 : 0;
#pragma unroll
        for (int e = 0; e < NE; e++) if (e != i0 && p[e] > p[i1]) i1 = e;
        float w0 = p[i0], w1 = p[i1], winv = 1.f / (w0 + w1);
        topi[2 * t] = i0;     topw[2 * t] = w0 * winv;
        topi[2 * t + 1] = i1; topw[2 * t + 1] = w1 * winv;
        atomicAdd(&cnt[i0], 1);
        atomicAdd(&cnt[i1], 1);
    }
}

// ---------------- scan ----------------
__global__ __launch_bounds__(256) void k_scan(const float* __restrict__ probs,
                                              const int* __restrict__ cnt,
                                              int* __restrict__ poff,
                                              int* __restrict__ texp,
                                              int* __restrict__ texp2,
                                              int* __restrict__ ntp,
                                              float* __restrict__ aux_out) {
    __shared__ float red[256 * NE];
    int tid = threadIdx.x;
    float part[NE];
#pragma unroll
    for (int e = 0; e < NE; e++) part[e] = 0.f;
    for (int t = tid; t < T_TOK; t += 256) {
#pragma unroll
        for (int e = 0; e < NE; e++) part[e] += probs[t * NE + e];
    }
#pragma unroll
    for (int e = 0; e < NE; e++) red[tid * NE + e] = part[e];
    __syncthreads();
    for (int s2 = 128; s2 > 0; s2 >>= 1) {
        if (tid < s2) {
#pragma unroll
            for (int e = 0; e < NE; e++) red[tid * NE + e] += red[(tid + s2) * NE + e];
        }
        __syncthreads();
    }
    if (tid == 0) {
        float al = 0.f;
#pragma unroll
        for (int e = 0; e < NE; e++) al += red[e] * (float)cnt[e];
        *aux_out = al * (8.0f / (16777216.0f + 1e-6f));
        int run = 0, tix = 0;
        for (int e = 0; e < NE; e++) {
            poff[e] = run;
            int nt = (cnt[e] + BM - 1) / BM;
            for (int i = 0; i < nt; i++) texp[tix++] = e;
            run += nt * BM;
        }
        ntp[0] = run / BM;      // # of 256-row tiles
        ntp[1] = run / 128;     // # of 128-row tiles
        for (int j = 0; j < MAXT2; j++) texp2[j] = (j >> 1) < tix ? texp[j >> 1] : 0;
    }
}

// ---------------- assign: token -> packed slot (+ inverse map) ----------------
__global__ __launch_bounds__(256) void k_assign(const int* __restrict__ topi,
                                                const float* __restrict__ topw,
                                                const int* __restrict__ poff,
                                                int* __restrict__ fill,
                                                int* __restrict__ row_tok,
                                                int* __restrict__ tok2row) {
    int t = blockIdx.x * 256 + threadIdx.x;
    if (t >= T_TOK) return;
#pragma unroll
    for (int k = 0; k < 2; k++) {
        int e = topi[2 * t + k];
        int pos = atomicAdd(&fill[e], 1);
        int r = poff[e] + pos;
        row_tok[r] = t;
        tok2row[2 * t + k] = r;
    }
}

// convert fp32 [rows][row_len] -> tile-ordered swizzled fp16 64x64 chunks
// (round-15 proven form: coalesced 16B reads, 8B swizzled writes)
__global__ __launch_bounds__(256) void k_convert(const float* __restrict__ src,
                                                 ushort* __restrict__ dst,
                                                 int row_len) {
    int nk = row_len >> 6;
    int kt = blockIdx.x, rt = blockIdx.y;
    int tid = threadIdx.x;
    int c0 = (tid & 15) * 4;                    // 4 floats per lane
    char* chunk = (char*)dst + ((size_t)rt * nk + kt) * CHUNK_B;
#pragma unroll
    for (int rr = 0; rr < 4; rr++) {
        int r = (tid >> 4) + rr * 16;
        const float* s = src + (size_t)(rt * 64 + r) * row_len + kt * 64 + c0;
        float4 v = *(const float4*)s;
        uint2 p;
        p.x = pk2(v.x, v.y);
        p.y = pk2(v.z, v.w);
        int sw = (r & 7) << 4;
        *(uint2*)(chunk + r * 128 + ((c0 * 2) ^ sw)) = p;
    }
}

// gather x rows into [256][64] swizzled fp16 chunks (rt, kt)
__global__ __launch_bounds__(512) void k_gather_t(const float* __restrict__ x,
                                                  const int* __restrict__ row_tok,
                                                  ushort* __restrict__ xg) {
    int kt = blockIdx.x, rt = blockIdx.y;
    int tid = threadIdx.x;
    int r = tid >> 1, c0 = (tid & 1) * 32;
    int tok = row_tok[rt * BM + r];
    char* chunk = (char*)xg + ((size_t)rt * 16 + kt) * ACH_B;
    int sw = (r & 7) << 4;
    if (tok >= 0) {
        const float* s = x + (size_t)tok * DM + kt * 64 + c0;
#pragma unroll
        for (int j = 0; j < 4; j++) {
            float4 va = *(const float4*)(s + j * 8);
            float4 vb = *(const float4*)(s + j * 8 + 4);
            *(uint4*)(chunk + r * 128 + ((c0 * 2 + j * 16) ^ sw)) = pack8f(va, vb);
        }
    } else {
        uint4 z = {0, 0, 0, 0};
#pragma unroll
        for (int j = 0; j < 4; j++)
            *(uint4*)(chunk + r * 128 + ((c0 * 2 + j * 16) ^ sw)) = z;
    }
}

// ============ GEMM1: 256 rows x 128 f-cols, dual-B, 8-phase ring-2 (FROZEN) ============
__global__ __launch_bounds__(512, 2) void k_g1(const ushort* __restrict__ xg,
                                               const ushort* __restrict__ W1h,
                                               const ushort* __restrict__ W3h,
                                               const int* __restrict__ texp,
                                               const int* __restrict__ ntp,
                                               ushort* __restrict__ hbuf) {
    __shared__ __align__(16) char lds[131072];
    int b = blockIdx.x;
    int xcd = b & 7, s = b >> 3;
    int rt = (s >> 5) * 8 + ((s >> 2) & 7);     // rt-groups of 8, shared by all XCDs
    int ct = xcd * 4 + (s & 3);                 // XCD-private ct-quad
    if (rt >= ntp[0]) return;                    // unpopulated tile
    int e = texp[rt];
    int tid = threadIdx.x, lane = tid & 63, wv = tid >> 6;
    int wr = wv >> 1, wc = wv & 1;

    const char* Ac  = (const char*)xg + (size_t)rt * 16 * ACH_B;
    const char* B1c = (const char*)W1h + ((size_t)(e * 64 + ct * 2) * 16) * CHUNK_B;
    const char* B3c = (const char*)W3h + ((size_t)(e * 64 + ct * 2) * 16) * CHUNK_B;

    const f32x4 fz = {0.f, 0.f, 0.f, 0.f};
    f32x4 acc1[4][4], acc3[4][4];
#pragma unroll
    for (int m = 0; m < 4; m++)
#pragma unroll
        for (int n = 0; n < 4; n++) { acc1[m][n] = fz; acc3[m][n] = fz; }

    f16x8 af[4], bf[4];
    int kb_base = (lane >> 4) * 16;

#define ST_A(kt_, b_, h_) {                                                        \
        const char* s_ = Ac + (kt_) * ACH_B + (h_) * 16384 + wv * 2048 + lane * 16; \
        char* d_ = lds + (b_) * 65536 + (h_) * 16384 + wv * 2048;                   \
        gll16(s_, d_); gll16(s_ + 1024, d_ + 1024); }
#define ST_B(Bc_, kt_, b_, off_) {                                                          \
        gll16(Bc_ + (kt_) * 8192 + wv * 1024 + lane * 16,                                    \
              lds + (b_) * 65536 + (off_) + wv * 1024);                                      \
        gll16(Bc_ + 131072 + (kt_) * 8192 + wv * 1024 + lane * 16,                           \
              lds + (b_) * 65536 + (off_) + 8192 + wv * 1024); }
#define DS_A(b_, ks_) _Pragma("unroll") for (int m = 0; m < 4; m++) {              \
        int r_ = wr * 64 + m * 16 + (lane & 15);                                   \
        af[m] = *(const f16x8*)(lds + (b_) * 65536 + r_ * 128 +                    \
                                 (((ks_) * 64 + kb_base) ^ ((r_ & 7) << 4))); }
#define DS_B(b_, off_, ks_) _Pragma("unroll") for (int n = 0; n < 4; n++) {        \
        int c_ = wc * 64 + n * 16 + (lane & 15);                                   \
        bf[n] = *(const f16x8*)(lds + (b_) * 65536 + (off_) + c_ * 128 +           \
                                 (((ks_) * 64 + kb_base) ^ ((c_ & 7) << 4))); }
#define MM(accX) _Pragma("unroll") for (int n = 0; n < 4; n++)                     \
        _Pragma("unroll") for (int m = 0; m < 4; m++)                              \
            accX[m][n] = MFMA16(af[m], bf[n], accX[m][n]);

    ST_A(0, 0, 0); ST_A(0, 0, 1); ST_B(B1c, 0, 0, 32768); ST_B(B3c, 0, 0, 49152);
    VMCNT(2);
    RAW_BAR();

    for (int it = 0; it < 8; ++it) {
        int t1 = 2 * it + 1;
        int t2 = 2 * it + 2;
        DS_A(0, 0); DS_B(0, 32768, 0);
        ST_A(t1, 1, 0);
        RAW_BAR();
        __builtin_amdgcn_s_setprio(1); MM(acc1); __builtin_amdgcn_s_setprio(0);
        VMCNT(2);
        RAW_BAR();
        DS_B(0, 49152, 0);
        ST_A(t1, 1, 1);
        RAW_BAR();
        __builtin_amdgcn_s_setprio(1); MM(acc3); __builtin_amdgcn_s_setprio(0);
        RAW_BAR();
        DS_A(0, 1); DS_B(0, 32768, 1);
        ST_B(B1c, t1, 1, 32768);
        RAW_BAR();
        __builtin_amdgcn_s_setprio(1); MM(acc1); __builtin_amdgcn_s_setprio(0);
        RAW_BAR();
        DS_B(0, 49152, 1);
        ST_B(B3c, t1, 1, 49152);
        RAW_BAR();
        __builtin_amdgcn_s_setprio(1); MM(acc3); __builtin_amdgcn_s_setprio(0);
        VMCNT(2);
        RAW_BAR();
        DS_A(1, 0); DS_B(1, 32768, 0);
        if (it < 7) ST_A(t2, 0, 0);
        RAW_BAR();
        __builtin_amdgcn_s_setprio(1); MM(acc1); __builtin_amdgcn_s_setprio(0);
        if (it < 7) { VMCNT(2); } else { VMCNT(0); }
        RAW_BAR();
        DS_B(1, 49152, 0);
        if (it < 7) ST_A(t2, 0, 1);
        RAW_BAR();
        __builtin_amdgcn_s_setprio(1); MM(acc3); __builtin_amdgcn_s_setprio(0);
        RAW_BAR();
        DS_A(1, 1); DS_B(1, 32768, 1);
        if (it < 7) ST_B(B1c, t2, 0, 32768);
        RAW_BAR();
        __builtin_amdgcn_s_setprio(1); MM(acc1); __builtin_amdgcn_s_setprio(0);
        RAW_BAR();
        DS_B(1, 49152, 1);
        if (it < 7) ST_B(B3c, t2, 0, 49152);
        RAW_BAR();
        __builtin_amdgcn_s_setprio(1); MM(acc3); __builtin_amdgcn_s_setprio(0);
        if (it < 7) { VMCNT(2); }
        RAW_BAR();
    }
#undef ST_A
#undef ST_B
#undef DS_A
#undef DS_B
#undef MM

    // epilogue: silu(a1)*a3 -> hbuf chunks (rt, ct*2 + fl/64), swizzled fp16
#pragma unroll
    for (int m = 0; m < 4; m++) {
#pragma unroll
        for (int i = 0; i < 4; i++) {
            int rl = wr * 64 + m * 16 + (lane >> 4) * 4 + i;   // 0..255
            int sw = (rl & 7) << 4;
#pragma unroll
            for (int n = 0; n < 4; n++) {
                int fl = wc * 64 + n * 16 + (lane & 15);        // 0..127
                float a1 = acc1[m][n][i], a3 = acc3[m][n][i];
                float h = (a1 / (1.f + expf(-a1))) * a3;
                char* hc = (char*)hbuf + ((size_t)rt * 64 + ct * 2 + (fl >> 6)) * ACH_B;
                *(ushort*)(hc + rl * 128 + ((2 * (fl & 63)) ^ sw)) = f2h_bits(h);
            }
        }
    }
}

// ===== GEMM2: 128x128, 4 waves, ring-2, NO atomics, fp32 B reg-staged (no W2h) =====
__global__ __launch_bounds__(256, 2) void k_g2(const ushort* __restrict__ hbuf,
                                               const float* __restrict__ W2,
                                               const int* __restrict__ texp2,
                                               const int* __restrict__ ntp,
                                               float* __restrict__ ybuf) {
    __shared__ __align__(16) char lds[65536];   // buf b: A @ b*32768, B fp16 image @ +16384
    int b = blockIdx.x;
    int xcd = b & 7, s = b >> 3;                // s in [0,80)
    int rt2 = (s >> 3) * 8 + xcd;               // strided bands (round-15 best decode)
    int ct = s & 7;                              // 128 cols of DM
    if (rt2 >= ntp[1]) return;                   // unpopulated tile
    int e = texp2[rt2];
    int tid = threadIdx.x, lane = tid & 63, wv = tid >> 6;   // wv 0..3
    int wr = wv >> 1, wc = wv & 1;              // wave tile 64x64

    const char* Ac = (const char*)hbuf + ((size_t)(rt2 >> 1) * 64) * ACH_B + (rt2 & 1) * 16384;
    // fp32 B: thread stages row bc (0..127 = W2 col within ct slice), k-half bk
    int bc = tid >> 1;
    int bk = (tid & 1) * 32;                    // float offset within 64-k window
    const float* Bg = W2 + ((size_t)e * DM + ct * 128 + bc) * DF + bk;
    int bso = 16384 + bc * 128;                 // LDS row base (matches DS2_B layout)
    int bsw = (bc & 7) << 4;

    const f32x4 fz = {0.f, 0.f, 0.f, 0.f};
    f32x4 acc[4][4];
#pragma unroll
    for (int m = 0; m < 4; m++)
#pragma unroll
        for (int n = 0; n < 4; n++) acc[m][n] = fz;

    f16x8 af[4], bf[4];
    float4 br[8];
    int kb_base = (lane >> 4) * 16;

#define ST2_A(kt_, b_) {                                                             \
        const char* s_ = Ac + (size_t)(kt_) * ACH_B + wv * 4096 + lane * 16;         \
        char* d_ = lds + (b_) * 32768 + wv * 4096;                                   \
        gll16(s_, d_); gll16(s_ + 1024, d_ + 1024);                                  \
        gll16(s_ + 2048, d_ + 2048); gll16(s_ + 3072, d_ + 3072); }
#define BLOAD(kt_) {                                                                 \
        const float* p_ = Bg + (size_t)(kt_) * 64;                                   \
        _Pragma("unroll")                                                            \
        for (int j = 0; j < 8; j++) br[j] = *(const float4*)(p_ + j * 4); }
#define BWRITE(b_) {                                                                 \
        char* base_ = lds + (b_) * 32768 + bso;                                      \
        *(uint4*)(base_ + ((2 * (bk + 0))  ^ bsw)) = pack8f(br[0], br[1]);           \
        *(uint4*)(base_ + ((2 * (bk + 8))  ^ bsw)) = pack8f(br[2], br[3]);           \
        *(uint4*)(base_ + ((2 * (bk + 16)) ^ bsw)) = pack8f(br[4], br[5]);           \
        *(uint4*)(base_ + ((2 * (bk + 24)) ^ bsw)) = pack8f(br[6], br[7]); }
#define DS2_A(b_, ks_) _Pragma("unroll") for (int m = 0; m < 4; m++) {               \
        int r_ = wr * 64 + m * 16 + (lane & 15);                                     \
        af[m] = *(const f16x8*)(lds + (b_) * 32768 + r_ * 128 +                      \
                                 (((ks_) * 64 + kb_base) ^ ((r_ & 7) << 4))); }
#define DS2_B(b_, ks_) _Pragma("unroll") for (int n = 0; n < 4; n++) {               \
        int c_ = wc * 64 + n * 16 + (lane & 15);                                     \
        bf[n] = *(const f16x8*)(lds + (b_) * 32768 + 16384 + c_ * 128 +              \
                                 (((ks_) * 64 + kb_base) ^ ((c_ & 7) << 4))); }
#define MM2() _Pragma("unroll") for (int n = 0; n < 4; n++)                          \
        _Pragma("unroll") for (int m = 0; m < 4; m++)                                \
            acc[m][n] = MFMA16(af[m], bf[n], acc[m][n]);

    // prologue: stage tile 0 (A via gll16; B via regs -> LDS)
    BLOAD(0);
    ST2_A(0, 0);
    VMCNT(0);
    BWRITE(0);
    LGKMCNT0();
    RAW_BAR();

    for (int t = 0; t < 64; ++t) {
        int cur = t & 1;
        // phA: ks0 | issue A(t+1) gll16 + B(t+1) fp32 loads
        DS2_A(cur, 0); DS2_B(cur, 0);
        if (t < 63) { ST2_A(t + 1, cur ^ 1); BLOAD(t + 1); }
        RAW_BAR();
        __builtin_amdgcn_s_setprio(1); MM2(); __builtin_amdgcn_s_setprio(0);
        RAW_BAR();
        // phB: ks1 (loads for t+1 keep flying under these MFMAs)
        DS2_A(cur, 1); DS2_B(cur, 1);
        RAW_BAR();
        __builtin_amdgcn_s_setprio(1); MM2(); __builtin_amdgcn_s_setprio(0);
        if (t < 63) {
            VMCNT(0);              // A(t+1) in LDS, B(t+1) in regs
            BWRITE(cur ^ 1);       // pack fp32->fp16 into next buffer
            LGKMCNT0();            // ds_writes visible before barrier
        }
        RAW_BAR();
    }
#undef ST2_A
#undef BLOAD
#undef BWRITE
#undef DS2_A
#undef DS2_B
#undef MM2

    // epilogue: plain fp32 stores into ybuf (each row written by exactly one block)
#pragma unroll
    for (int m = 0; m < 4; m++) {
#pragma unroll
        for (int i = 0; i < 4; i++) {
            int rr = rt2 * 128 + wr * 64 + m * 16 + (lane >> 4) * 4 + i;
            float* yrow = ybuf + (size_t)rr * DM + ct * 128 + wc * 64 + (lane & 15);
#pragma unroll
            for (int n = 0; n < 4; n++) yrow[n * 16] = acc[m][n][i];
        }
    }
}

// ---------------- combine: out[t] = w0*y[r0] + w1*y[r1] ----------------
__global__ __launch_bounds__(256) void k_combine(const float* __restrict__ ybuf,
                                                 const int* __restrict__ tok2row,
                                                 const float* __restrict__ topw,
                                                 float* __restrict__ out) {
    int t = blockIdx.x;
    int i = threadIdx.x * 4;
    int r0 = tok2row[2 * t], r1 = tok2row[2 * t + 1];
    float w0 = topw[2 * t], w1 = topw[2 * t + 1];
    float4 a = *(const float4*)(ybuf + (size_t)r0 * DM + i);
    float4 c = *(const float4*)(ybuf + (size_t)r1 * DM + i);
    float4 o;
    o.x = w0 * a.x + w1 * c.x;
    o.y = w0 * a.y + w1 * c.y;
    o.z = w0 * a.z + w1 * c.z;
    o.w = w0 * a.w + w1 * c.w;
    *(float4*)(out + (size_t)t * DM + i) = o;
}

extern "C" void kernel_launch(void* const* d_in, const int* in_sizes, int n_in,
                              void* d_out, int out_size, void* d_ws, size_t ws_size,
                              hipStream_t stream) {
    (void)in_sizes; (void)n_in; (void)out_size; (void)ws_size;
    const float* x  = (const float*)d_in[0];
    const float* Wr = (const float*)d_in[1];
    const float* W1 = (const float*)d_in[2];
    const float* W2 = (const float*)d_in[3];
    const float* W3 = (const float*)d_in[4];
    float* out = (float*)d_out;
    char* ws = (char*)d_ws;

    int* misc  = (int*)ws;   // cnt[8] fill[8] poff[8] texp[40]@24 texp2[80]@64 ntp[2]@144
    int* cnt   = misc;
    int* fill  = misc + 8;
    int* poff  = misc + 16;
    int* texp  = misc + 24;
    int* texp2 = misc + 64;
    int* ntp   = misc + 144;
    int*    topi    = (int*)(ws + 1024);
    float*  topw    = (float*)(ws + 33792);
    int*    tok2row = (int*)(ws + 66560);        // dead-probs alias
    float*  probs   = (float*)(ws + 99328);      // 128 KB
    int*    row_tok = (int*)(ws + 230400);       // RCAP ints
    ushort* hbuf    = (ushort*)(ws + 271360);    // 83.9 MB
    ushort* W1h     = (ushort*)(ws + 84157440);  // 64 MB (dead after k_g1)
    float*  ybuf    = (float*)(ws + 84157440);   // 41.9 MB, aliases W1h
    ushort* W3h     = (ushort*)(ws + 151266304); // 64 MB
    ushort* xg      = (ushort*)(ws + 218375168); // 21 MB

    k_init<<<(RCAP + 255) / 256, 256, 0, stream>>>(misc, row_tok);
    k_router<<<T_TOK, 64, 0, stream>>>(x, Wr, probs, topi, topw, cnt);
    k_scan<<<1, 256, 0, stream>>>(probs, cnt, poff, texp, texp2, ntp, out + (size_t)T_TOK * DM);
    k_assign<<<(T_TOK + 255) / 256, 256, 0, stream>>>(topi, topw, poff, fill, row_tok, tok2row);

    k_convert<<<dim3(16, 512), 256, 0, stream>>>(W1, W1h, DM);
    k_convert<<<dim3(16, 512), 256, 0, stream>>>(W3, W3h, DM);
    k_gather_t<<<dim3(16, MAXT), 512, 0, stream>>>(x, row_tok, xg);
    k_g1<<<1280, 512, 0, stream>>>(xg, W1h, W3h, texp, ntp, hbuf);
    k_g2<<<640, 256, 0, stream>>>(hbuf, W2, texp2, ntp, ybuf);
    k_combine<<<T_TOK, 256, 0, stream>>>(ybuf, tok2row, topw, out);
}

// Round 21
// 611.998 us; speedup vs baseline: 1.1823x; 1.1823x over previous
//
#include <hip/hip_runtime.h>

#define T_TOK 4096
#define DM 1024
#define DF 4096
#define NE 8
#define BM 256
#define RCAP 10240      // 8192 + 8*256 worst-case padding
#define MAXT 40         // RCAP / BM (256-row tiles)
#define MAXT2 80        // RCAP / 128 (128-row tiles, gemm2)
#define ACH_B 32768     // [256][64] fp16 swizzled A-chunk
#define CHUNK_B 8192    // [64][64] fp16 swizzled weight chunk

typedef _Float16 f16x8 __attribute__((ext_vector_type(8)));
typedef float f32x4 __attribute__((ext_vector_type(4)));

#define MFMA16(a, b, c) __builtin_amdgcn_mfma_f32_16x16x32_f16(a, b, c, 0, 0, 0)
#define RAW_BAR() __builtin_amdgcn_s_barrier()
#define VMCNT(n) asm volatile("s_waitcnt vmcnt(" #n ")" ::: "memory")

__device__ __forceinline__ ushort f2h_bits(float f) {
    _Float16 h = (_Float16)f;
    return __builtin_bit_cast(unsigned short, h);
}

__device__ __forceinline__ unsigned int pk2(float a, float b) {
    return __builtin_bit_cast(unsigned int, __builtin_amdgcn_cvt_pkrtz(a, b));
}

__device__ __forceinline__ uint4 pack8f(float4 a, float4 b) {
    uint4 r;
    r.x = pk2(a.x, a.y); r.y = pk2(a.z, a.w);
    r.z = pk2(b.x, b.y); r.w = pk2(b.z, b.w);
    return r;
}

// async global->LDS, 16B per lane; lds ptr wave-uniform
__device__ __forceinline__ void gll16(const void* g, void* l) {
    __builtin_amdgcn_global_load_lds(
        (const __attribute__((address_space(1))) unsigned int*)g,
        (__attribute__((address_space(3))) unsigned int*)l, 16, 0, 0);
}

// ---------------- init ----------------
__global__ __launch_bounds__(256) void k_init(int* __restrict__ misc,
                                              int* __restrict__ row_tok) {
    int i = blockIdx.x * 256 + threadIdx.x;
    if (i < RCAP) row_tok[i] = -1;
    if (i < 256) misc[i] = 0;   // cnt8 fill8 poff8 texp40 texp2_80 ntp2
}

// ---------------- router ----------------
__global__ __launch_bounds__(64) void k_router(const float* __restrict__ x,
                                               const float* __restrict__ Wr,
                                               float* __restrict__ probs,
                                               int* __restrict__ topi,
                                               float* __restrict__ topw,
                                               int* __restrict__ cnt) {
    int t = blockIdx.x;
    int lane = threadIdx.x;
    const float* xr = x + (size_t)t * DM;
    float s[NE];
#pragma unroll
    for (int e = 0; e < NE; e++) s[e] = 0.f;
    for (int j = lane; j < DM; j += 64) {
        float xv = xr[j];
#pragma unroll
        for (int e = 0; e < NE; e++) s[e] += xv * Wr[e * DM + j];
    }
#pragma unroll
    for (int off = 32; off > 0; off >>= 1) {
#pragma unroll
        for (int e = 0; e < NE; e++) s[e] += __shfl_xor(s[e], off, 64);
    }
    if (lane == 0) {
        float mx = s[0];
#pragma unroll
        for (int e = 1; e < NE; e++) mx = fmaxf(mx, s[e]);
        float ex[NE], sum = 0.f;
#pragma unroll
        for (int e = 0; e < NE; e++) { ex[e] = expf(s[e] - mx); sum += ex[e]; }
        float inv = 1.f / sum;
        float p[NE];
#pragma unroll
        for (int e = 0; e < NE; e++) { p[e] = ex[e] * inv; probs[t * NE + e] = p[e]; }
        int i0 = 0;
#pragma unroll
        for (int e = 1; e < NE; e++) if (p[e] > p[i0]) i0 = e;
        int i1 = (i0 == 0) ? 1 : 0;
#pragma unroll
        for (int e = 0; e < NE; e++) if (e != i0 && p[e] > p[i1]) i1 = e;
        float w0 = p[i0], w1 = p[i1], winv = 1.f / (w0 + w1);
        topi[2 * t] = i0;     topw[2 * t] = w0 * winv;
        topi[2 * t + 1] = i1; topw[2 * t + 1] = w1 * winv;
        atomicAdd(&cnt[i0], 1);
        atomicAdd(&cnt[i1], 1);
    }
}

// ---------------- scan ----------------
__global__ __launch_bounds__(256) void k_scan(const float* __restrict__ probs,
                                              const int* __restrict__ cnt,
                                              int* __restrict__ poff,
                                              int* __restrict__ texp,
                                              int* __restrict__ texp2,
                                              int* __restrict__ ntp,
                                              float* __restrict__ aux_out) {
    __shared__ float red[256 * NE];
    int tid = threadIdx.x;
    float part[NE];
#pragma unroll
    for (int e = 0; e < NE; e++) part[e] = 0.f;
    for (int t = tid; t < T_TOK; t += 256) {
#pragma unroll
        for (int e = 0; e < NE; e++) part[e] += probs[t * NE + e];
    }
#pragma unroll
    for (int e = 0; e < NE; e++) red[tid * NE + e] = part[e];
    __syncthreads();
    for (int s2 = 128; s2 > 0; s2 >>= 1) {
        if (tid < s2) {
#pragma unroll
            for (int e = 0; e < NE; e++) red[tid * NE + e] += red[(tid + s2) * NE + e];
        }
        __syncthreads();
    }
    if (tid == 0) {
        float al = 0.f;
#pragma unroll
        for (int e = 0; e < NE; e++) al += red[e] * (float)cnt[e];
        *aux_out = al * (8.0f / (16777216.0f + 1e-6f));
        int run = 0, tix = 0;
        for (int e = 0; e < NE; e++) {
            poff[e] = run;
            int nt = (cnt[e] + BM - 1) / BM;
            for (int i = 0; i < nt; i++) texp[tix++] = e;
            run += nt * BM;
        }
        ntp[0] = run / BM;      // # of 256-row tiles
        ntp[1] = run / 128;     // # of 128-row tiles
        for (int j = 0; j < MAXT2; j++) texp2[j] = (j >> 1) < tix ? texp[j >> 1] : 0;
    }
}

// ---------------- assign: token -> packed slot (+ inverse map) ----------------
__global__ __launch_bounds__(256) void k_assign(const int* __restrict__ topi,
                                                const float* __restrict__ topw,
                                                const int* __restrict__ poff,
                                                int* __restrict__ fill,
                                                int* __restrict__ row_tok,
                                                int* __restrict__ tok2row) {
    int t = blockIdx.x * 256 + threadIdx.x;
    if (t >= T_TOK) return;
#pragma unroll
    for (int k = 0; k < 2; k++) {
        int e = topi[2 * t + k];
        int pos = atomicAdd(&fill[e], 1);
        int r = poff[e] + pos;
        row_tok[r] = t;
        tok2row[2 * t + k] = r;
    }
}

// convert fp32 [rows][row_len] -> tile-ordered swizzled fp16 64x64 chunks
// fully coalesced: 16 lanes cover one 256B fp32 row segment; 8B swizzled writes
__global__ __launch_bounds__(256) void k_convert(const float* __restrict__ src,
                                                 ushort* __restrict__ dst,
                                                 int row_len) {
    int nk = row_len >> 6;
    int kt = blockIdx.x, rt = blockIdx.y;
    int tid = threadIdx.x;
    int c0 = (tid & 15) * 4;                    // 4 floats per lane
    char* chunk = (char*)dst + ((size_t)rt * nk + kt) * CHUNK_B;
#pragma unroll
    for (int rr = 0; rr < 4; rr++) {
        int r = (tid >> 4) + rr * 16;
        const float* s = src + (size_t)(rt * 64 + r) * row_len + kt * 64 + c0;
        float4 v = *(const float4*)s;
        uint2 p;
        p.x = pk2(v.x, v.y);
        p.y = pk2(v.z, v.w);
        int sw = (r & 7) << 4;
        *(uint2*)(chunk + r * 128 + ((c0 * 2) ^ sw)) = p;
    }
}

// gather x rows into [256][64] swizzled fp16 chunks (rt, kt)
__global__ __launch_bounds__(512) void k_gather_t(const float* __restrict__ x,
                                                  const int* __restrict__ row_tok,
                                                  ushort* __restrict__ xg) {
    int kt = blockIdx.x, rt = blockIdx.y;
    int tid = threadIdx.x;
    int r = tid >> 1, c0 = (tid & 1) * 32;
    int tok = row_tok[rt * BM + r];
    char* chunk = (char*)xg + ((size_t)rt * 16 + kt) * ACH_B;
    int sw = (r & 7) << 4;
    if (tok >= 0) {
        const float* s = x + (size_t)tok * DM + kt * 64 + c0;
#pragma unroll
        for (int j = 0; j < 4; j++) {
            float4 va = *(const float4*)(s + j * 8);
            float4 vb = *(const float4*)(s + j * 8 + 4);
            *(uint4*)(chunk + r * 128 + ((c0 * 2 + j * 16) ^ sw)) = pack8f(va, vb);
        }
    } else {
        uint4 z = {0, 0, 0, 0};
#pragma unroll
        for (int j = 0; j < 4; j++)
            *(uint4*)(chunk + r * 128 + ((c0 * 2 + j * 16) ^ sw)) = z;
    }
}

// ============ GEMM1: 256 rows x 128 f-cols, dual-B, 8-phase ring-2 (FROZEN) ============
__global__ __launch_bounds__(512, 2) void k_g1(const ushort* __restrict__ xg,
                                               const ushort* __restrict__ W1h,
                                               const ushort* __restrict__ W3h,
                                               const int* __restrict__ texp,
                                               const int* __restrict__ ntp,
                                               ushort* __restrict__ hbuf) {
    __shared__ __align__(16) char lds[131072];
    int b = blockIdx.x;
    int xcd = b & 7, s = b >> 3;
    int rt = (s >> 5) * 8 + ((s >> 2) & 7);     // rt-groups of 8, shared by all XCDs
    int ct = xcd * 4 + (s & 3);                 // XCD-private ct-quad
    if (rt >= ntp[0]) return;                    // unpopulated tile
    int e = texp[rt];
    int tid = threadIdx.x, lane = tid & 63, wv = tid >> 6;
    int wr = wv >> 1, wc = wv & 1;

    const char* Ac  = (const char*)xg + (size_t)rt * 16 * ACH_B;
    const char* B1c = (const char*)W1h + ((size_t)(e * 64 + ct * 2) * 16) * CHUNK_B;
    const char* B3c = (const char*)W3h + ((size_t)(e * 64 + ct * 2) * 16) * CHUNK_B;

    const f32x4 fz = {0.f, 0.f, 0.f, 0.f};
    f32x4 acc1[4][4], acc3[4][4];
#pragma unroll
    for (int m = 0; m < 4; m++)
#pragma unroll
        for (int n = 0; n < 4; n++) { acc1[m][n] = fz; acc3[m][n] = fz; }

    f16x8 af[4], bf[4];
    int kb_base = (lane >> 4) * 16;

#define ST_A(kt_, b_, h_) {                                                        \
        const char* s_ = Ac + (kt_) * ACH_B + (h_) * 16384 + wv * 2048 + lane * 16; \
        char* d_ = lds + (b_) * 65536 + (h_) * 16384 + wv * 2048;                   \
        gll16(s_, d_); gll16(s_ + 1024, d_ + 1024); }
#define ST_B(Bc_, kt_, b_, off_) {                                                          \
        gll16(Bc_ + (kt_) * 8192 + wv * 1024 + lane * 16,                                    \
              lds + (b_) * 65536 + (off_) + wv * 1024);                                      \
        gll16(Bc_ + 131072 + (kt_) * 8192 + wv * 1024 + lane * 16,                           \
              lds + (b_) * 65536 + (off_) + 8192 + wv * 1024); }
#define DS_A(b_, ks_) _Pragma("unroll") for (int m = 0; m < 4; m++) {              \
        int r_ = wr * 64 + m * 16 + (lane & 15);                                   \
        af[m] = *(const f16x8*)(lds + (b_) * 65536 + r_ * 128 +                    \
                                 (((ks_) * 64 + kb_base) ^ ((r_ & 7) << 4))); }
#define DS_B(b_, off_, ks_) _Pragma("unroll") for (int n = 0; n < 4; n++) {        \
        int c_ = wc * 64 + n * 16 + (lane & 15);                                   \
        bf[n] = *(const f16x8*)(lds + (b_) * 65536 + (off_) + c_ * 128 +           \
                                 (((ks_) * 64 + kb_base) ^ ((c_ & 7) << 4))); }
#define MM(accX) _Pragma("unroll") for (int n = 0; n < 4; n++)                     \
        _Pragma("unroll") for (int m = 0; m < 4; m++)                              \
            accX[m][n] = MFMA16(af[m], bf[n], accX[m][n]);

    ST_A(0, 0, 0); ST_A(0, 0, 1); ST_B(B1c, 0, 0, 32768); ST_B(B3c, 0, 0, 49152);
    VMCNT(2);
    RAW_BAR();

    for (int it = 0; it < 8; ++it) {
        int t1 = 2 * it + 1;
        int t2 = 2 * it + 2;
        DS_A(0, 0); DS_B(0, 32768, 0);
        ST_A(t1, 1, 0);
        RAW_BAR();
        __builtin_amdgcn_s_setprio(1); MM(acc1); __builtin_amdgcn_s_setprio(0);
        VMCNT(2);
        RAW_BAR();
        DS_B(0, 49152, 0);
        ST_A(t1, 1, 1);
        RAW_BAR();
        __builtin_amdgcn_s_setprio(1); MM(acc3); __builtin_amdgcn_s_setprio(0);
        RAW_BAR();
        DS_A(0, 1); DS_B(0, 32768, 1);
        ST_B(B1c, t1, 1, 32768);
        RAW_BAR();
        __builtin_amdgcn_s_setprio(1); MM(acc1); __builtin_amdgcn_s_setprio(0);
        RAW_BAR();
        DS_B(0, 49152, 1);
        ST_B(B3c, t1, 1, 49152);
        RAW_BAR();
        __builtin_amdgcn_s_setprio(1); MM(acc3); __builtin_amdgcn_s_setprio(0);
        VMCNT(2);
        RAW_BAR();
        DS_A(1, 0); DS_B(1, 32768, 0);
        if (it < 7) ST_A(t2, 0, 0);
        RAW_BAR();
        __builtin_amdgcn_s_setprio(1); MM(acc1); __builtin_amdgcn_s_setprio(0);
        if (it < 7) { VMCNT(2); } else { VMCNT(0); }
        RAW_BAR();
        DS_B(1, 49152, 0);
        if (it < 7) ST_A(t2, 0, 1);
        RAW_BAR();
        __builtin_amdgcn_s_setprio(1); MM(acc3); __builtin_amdgcn_s_setprio(0);
        RAW_BAR();
        DS_A(1, 1); DS_B(1, 32768, 1);
        if (it < 7) ST_B(B1c, t2, 0, 32768);
        RAW_BAR();
        __builtin_amdgcn_s_setprio(1); MM(acc1); __builtin_amdgcn_s_setprio(0);
        RAW_BAR();
        DS_B(1, 49152, 1);
        if (it < 7) ST_B(B3c, t2, 0, 49152);
        RAW_BAR();
        __builtin_amdgcn_s_setprio(1); MM(acc3); __builtin_amdgcn_s_setprio(0);
        if (it < 7) { VMCNT(2); }
        RAW_BAR();
    }
#undef ST_A
#undef ST_B
#undef DS_A
#undef DS_B
#undef MM

    // epilogue: silu(a1)*a3 -> hbuf chunks (rt, ct*2 + fl/64), swizzled fp16
#pragma unroll
    for (int m = 0; m < 4; m++) {
#pragma unroll
        for (int i = 0; i < 4; i++) {
            int rl = wr * 64 + m * 16 + (lane >> 4) * 4 + i;   // 0..255
            int sw = (rl & 7) << 4;
#pragma unroll
            for (int n = 0; n < 4; n++) {
                int fl = wc * 64 + n * 16 + (lane & 15);        // 0..127
                float a1 = acc1[m][n][i], a3 = acc3[m][n][i];
                float h = (a1 / (1.f + expf(-a1))) * a3;
                char* hc = (char*)hbuf + ((size_t)rt * 64 + ct * 2 + (fl >> 6)) * ACH_B;
                *(ushort*)(hc + rl * 128 + ((2 * (fl & 63)) ^ sw)) = f2h_bits(h);
            }
        }
    }
}

// ===== GEMM2: 128x128 tile, 4 waves, ring-2 counted pipeline, NO atomics (R16 FROZEN) =====
__global__ __launch_bounds__(256, 2) void k_g2(const ushort* __restrict__ hbuf,
                                               const ushort* __restrict__ W2h,
                                               const int* __restrict__ texp2,
                                               const int* __restrict__ ntp,
                                               float* __restrict__ ybuf) {
    __shared__ __align__(16) char lds[65536];   // 2 bufs x (A 16KB @0, B 16KB @16384)
    int b = blockIdx.x;
    int xcd = b & 7, s = b >> 3;
    int rt2 = (s >> 3) * 8 + xcd;               // strided bands: perfect balance
    int ct = s & 7;                              // 128 cols of DM
    if (rt2 >= ntp[1]) return;                   // unpopulated tile
    int e = texp2[rt2];
    int tid = threadIdx.x, lane = tid & 63, wv = tid >> 6;   // wv 0..3
    int wr = wv >> 1, wc = wv & 1;              // wave tile 64x64

    const char* Ac = (const char*)hbuf + ((size_t)(rt2 >> 1) * 64) * ACH_B + (rt2 & 1) * 16384;
    const char* Bc = (const char*)W2h + ((size_t)(e * 16 + ct * 2) * 64) * CHUNK_B;

    const f32x4 fz = {0.f, 0.f, 0.f, 0.f};
    f32x4 acc[4][4];
#pragma unroll
    for (int m = 0; m < 4; m++)
#pragma unroll
        for (int n = 0; n < 4; n++) acc[m][n] = fz;

    f16x8 af[4], bf[4];
    int kb_base = (lane >> 4) * 16;

#define ST2_A(kt_, b_) {                                                             \
        const char* s_ = Ac + (size_t)(kt_) * ACH_B + wv * 4096 + lane * 16;         \
        char* d_ = lds + (b_) * 32768 + wv * 4096;                                   \
        gll16(s_, d_); gll16(s_ + 1024, d_ + 1024);                                  \
        gll16(s_ + 2048, d_ + 2048); gll16(s_ + 3072, d_ + 3072); }
#define ST2_B(kt_, b_) {                                                             \
        const char* s0_ = Bc + (size_t)(kt_) * 8192 + wv * 2048 + lane * 16;         \
        char* d0_ = lds + (b_) * 32768 + 16384 + wv * 2048;                          \
        gll16(s0_, d0_); gll16(s0_ + 1024, d0_ + 1024);                              \
        const char* s1_ = Bc + 524288 + (size_t)(kt_) * 8192 + wv * 2048 + lane * 16; \
        char* d1_ = lds + (b_) * 32768 + 24576 + wv * 2048;                          \
        gll16(s1_, d1_); gll16(s1_ + 1024, d1_ + 1024); }
#define DS2_A(b_, ks_) _Pragma("unroll") for (int m = 0; m < 4; m++) {               \
        int r_ = wr * 64 + m * 16 + (lane & 15);                                     \
        af[m] = *(const f16x8*)(lds + (b_) * 32768 + r_ * 128 +                      \
                                 (((ks_) * 64 + kb_base) ^ ((r_ & 7) << 4))); }
#define DS2_B(b_, ks_) _Pragma("unroll") for (int n = 0; n < 4; n++) {               \
        int c_ = wc * 64 + n * 16 + (lane & 15);                                     \
        bf[n] = *(const f16x8*)(lds + (b_) * 32768 + 16384 + c_ * 128 +              \
                                 (((ks_) * 64 + kb_base) ^ ((c_ & 7) << 4))); }
#define MM2() _Pragma("unroll") for (int n = 0; n < 4; n++)                          \
        _Pragma("unroll") for (int m = 0; m < 4; m++)                                \
            acc[m][n] = MFMA16(af[m], bf[n], acc[m][n]);

    // prologue: stage tile 0
    ST2_A(0, 0); ST2_B(0, 0);
    VMCNT(0);
    RAW_BAR();

    for (int t = 0; t < 64; ++t) {
        int cur = t & 1;
        // phA: ks0 | stage full tile t+1 into other buffer
        DS2_A(cur, 0); DS2_B(cur, 0);
        if (t < 63) { ST2_A(t + 1, cur ^ 1); ST2_B(t + 1, cur ^ 1); }
        RAW_BAR();
        __builtin_amdgcn_s_setprio(1); MM2(); __builtin_amdgcn_s_setprio(0);
        RAW_BAR();
        // phB: ks1 (no staging; t+1's 8 loads keep flying)
        DS2_A(cur, 1); DS2_B(cur, 1);
        RAW_BAR();
        __builtin_amdgcn_s_setprio(1); MM2(); __builtin_amdgcn_s_setprio(0);
        if (t < 63) { VMCNT(0); }     // t+1 landed; had ~2 phases of cover
        RAW_BAR();
    }
#undef ST2_A
#undef ST2_B
#undef DS2_A
#undef DS2_B
#undef MM2

    // epilogue: plain fp32 stores into ybuf (each row written by exactly one block)
#pragma unroll
    for (int m = 0; m < 4; m++) {
#pragma unroll
        for (int i = 0; i < 4; i++) {
            int rr = rt2 * 128 + wr * 64 + m * 16 + (lane >> 4) * 4 + i;
            float* yrow = ybuf + (size_t)rr * DM + ct * 128 + wc * 64 + (lane & 15);
#pragma unroll
            for (int n = 0; n < 4; n++) yrow[n * 16] = acc[m][n][i];
        }
    }
}

// ---------------- combine: out[t] = w0*y[r0] + w1*y[r1] ----------------
__global__ __launch_bounds__(256) void k_combine(const float* __restrict__ ybuf,
                                                 const int* __restrict__ tok2row,
                                                 const float* __restrict__ topw,
                                                 float* __restrict__ out) {
    int t = blockIdx.x;
    int i = threadIdx.x * 4;
    int r0 = tok2row[2 * t], r1 = tok2row[2 * t + 1];
    float w0 = topw[2 * t], w1 = topw[2 * t + 1];
    float4 a = *(const float4*)(ybuf + (size_t)r0 * DM + i);
    float4 c = *(const float4*)(ybuf + (size_t)r1 * DM + i);
    float4 o;
    o.x = w0 * a.x + w1 * c.x;
    o.y = w0 * a.y + w1 * c.y;
    o.z = w0 * a.z + w1 * c.z;
    o.w = w0 * a.w + w1 * c.w;
    *(float4*)(out + (size_t)t * DM + i) = o;
}

extern "C" void kernel_launch(void* const* d_in, const int* in_sizes, int n_in,
                              void* d_out, int out_size, void* d_ws, size_t ws_size,
                              hipStream_t stream) {
    (void)in_sizes; (void)n_in; (void)out_size; (void)ws_size;
    const float* x  = (const float*)d_in[0];
    const float* Wr = (const float*)d_in[1];
    const float* W1 = (const float*)d_in[2];
    const float* W2 = (const float*)d_in[3];
    const float* W3 = (const float*)d_in[4];
    float* out = (float*)d_out;
    char* ws = (char*)d_ws;

    int* misc  = (int*)ws;   // cnt[8] fill[8] poff[8] texp[40]@24 texp2[80]@64 ntp[2]@144
    int* cnt   = misc;
    int* fill  = misc + 8;
    int* poff  = misc + 16;
    int* texp  = misc + 24;
    int* texp2 = misc + 64;
    int* ntp   = misc + 144;
    int*    topi    = (int*)(ws + 1024);
    float*  topw    = (float*)(ws + 33792);
    int*    tok2row = (int*)(ws + 66560);        // aliases probs head (dead after scan)
    float*  probs   = (float*)(ws + 99328);      // 128 KB
    int*    row_tok = (int*)(ws + 230400);       // RCAP ints
    ushort* hbuf    = (ushort*)(ws + 271360);    // 83.9 MB
    ushort* W1h     = (ushort*)(ws + 84157440);  // 64 MB (dead after k_g1)
    float*  ybuf    = (float*)(ws + 84157440);   // 41.9 MB, aliases W1h
    ushort* W3h     = (ushort*)(ws + 151266304); // 64 MB
    ushort* xg      = (ushort*)(ws + 218375168); // 21 MB (dead after k_g1)
    ushort* W2h     = (ushort*)(ws + 218375168); // 64 MB, aliases xg -> ends 285484032

    k_init<<<(RCAP + 255) / 256, 256, 0, stream>>>(misc, row_tok);
    k_router<<<T_TOK, 64, 0, stream>>>(x, Wr, probs, topi, topw, cnt);
    k_scan<<<1, 256, 0, stream>>>(probs, cnt, poff, texp, texp2, ntp, out + (size_t)T_TOK * DM);
    k_assign<<<(T_TOK + 255) / 256, 256, 0, stream>>>(topi, topw, poff, fill, row_tok, tok2row);

    k_convert<<<dim3(16, 512), 256, 0, stream>>>(W1, W1h, DM);
    k_convert<<<dim3(16, 512), 256, 0, stream>>>(W3, W3h, DM);
    k_gather_t<<<dim3(16, MAXT), 512, 0, stream>>>(x, row_tok, xg);
    k_g1<<<1280, 512, 0, stream>>>(xg, W1h, W3h, texp, ntp, hbuf);
    k_convert<<<dim3(64, 128), 256, 0, stream>>>(W2, W2h, DF);   // xg dead; W1h dead -> ybuf
    k_g2<<<640, 256, 0, stream>>>(hbuf, W2h, texp2, ntp, ybuf);
    k_combine<<<T_TOK, 256, 0, stream>>>(ybuf, tok2row, topw, out);
}